// Round 11
// baseline (224.696 us; speedup 1.0000x reference)
//
#include <hip/hip_runtime.h>
#include <hip/hip_bf16.h>

// Problem constants (fixed by the reference setup)
#define BGR  128           // graphs
#define NPG  111           // nodes per graph
#define EPG  (NPG*(NPG-1)) // 12210 directed edges per graph
#define H16S 136           // h16 (transposed h) row stride in halfs, 16B-aligned
#define HRS  40            // hrow (row-major h) stride in halfs, 16B-aligned

typedef _Float16 half8 __attribute__((ext_vector_type(8)));
typedef float    f32x4 __attribute__((ext_vector_type(4)));

// ---------------------------------------------------------------------------
// ONE kernel: whole 3-layer GAT + pool. One 1024-thread block per graph.
// 2 barriers per layer: phase A (proj-MFMA + ass/ads partials || diag from
// global) -> phase C (attention MFMA, eatt read directly from L2-hot global).
__global__ __launch_bounds__(1024, 1) void
gnn_all(const float* __restrict__ x, const float* __restrict__ ea,
        const float* __restrict__ W0, const float* __restrict__ as0, const float* __restrict__ ad0,
        const float* __restrict__ We0, const float* __restrict__ ae0, const float* __restrict__ b0,
        const float* __restrict__ W1, const float* __restrict__ as1, const float* __restrict__ ad1,
        const float* __restrict__ We1, const float* __restrict__ ae1, const float* __restrict__ b1,
        const float* __restrict__ W2, const float* __restrict__ as2, const float* __restrict__ ad2,
        const float* __restrict__ We2, const float* __restrict__ ae2, const float* __restrict__ b2,
        const float* __restrict__ linW, const float* __restrict__ linb,
        float* __restrict__ out)
{
    int g = blockIdx.x;
    int t = threadIdx.x;
    int wave = t >> 6, lane = t & 63;
    int m = lane & 15, quad = lane >> 4;

    __shared__ _Float16 h16[32 * H16S];    // 8704 B: h transposed [c][s]
    __shared__ _Float16 hrow[112 * HRS];   // 8960 B: h row-major [s][c]
    __shared__ float assP[2][112];         // ass partials (ct 0/1)
    __shared__ float adsP[2][112];
    __shared__ float diag[112];
    __shared__ float bsh[32];
    __shared__ float pool7[8];

    // init: h16 fully zero (pad cols 112..135 must stay 0); hrow pad row zero
    for (int i = t; i < 32 * H16S; i += 1024) h16[i] = (_Float16)0.f;
    if (t < 32) hrow[111 * HRS + t] = (_Float16)0.f;

    // layer-0 scalars: K_as = sum_c W0[c]*as0[c], K_ad likewise (din=1)
    float kr = (lane < 32) ? W0[lane] * as0[lane] : W0[lane & 31] * ad0[lane & 31];
    #pragma unroll
    for (int off = 1; off < 32; off <<= 1) kr += __shfl_xor(kr, off);
    float K_as = __shfl(kr, 0), K_ad = __shfl(kr, 32);

    const float2* eg2 = (const float2*)ea + (size_t)g * EPG;

    for (int l = 0; l < 3; l++) {
        const float* W  = (l == 0) ? W0  : ((l == 1) ? W1  : W2);
        const float* aS = (l == 0) ? as0 : ((l == 1) ? as1 : as2);
        const float* aD = (l == 0) ? ad0 : ((l == 1) ? ad1 : ad2);
        const float* Ne = (l == 0) ? We0 : ((l == 1) ? We1 : We2);
        const float* av = (l == 0) ? ae0 : ((l == 1) ? ae1 : ae2);
        const float* bb = (l == 0) ? b0  : ((l == 1) ? b1  : b2);

        // per-wave c0,c1 = We @ ae (redundant, no LDS, no barrier)
        float red = Ne[(lane >> 5) * 32 + (lane & 31)] * av[lane & 31];
        #pragma unroll
        for (int off = 1; off < 32; off <<= 1) red += __shfl_xor(red, off);
        float c0 = __shfl(red, 0), c1 = __shfl(red, 32);

        if (t < 32) bsh[t] = bb[t];

        // ===== phase A: proj (waves 0-13)  ||  diag (waves 14-15) ============
        if (wave < 14) {
            if (l == 0) {
                // outer product: h^T[c][s] = x[s]*W[c]; 896 threads x 4 iters
                int c = t & 31, sbase = t >> 5;          // sbase 0..27
                #pragma unroll
                for (int it = 0; it < 4; it++) {
                    int s = sbase + it * 28;             // 0..111
                    float hv = (s < NPG) ? x[g * NPG + s] * W[c] : 0.f;
                    h16[c * H16S + s] = (_Float16)hv;
                }
                if (t < 112) {                           // ass/ads via K scalars
                    float v = (t < NPG) ? x[g * NPG + t] : 0.f;
                    assP[0][t] = v * K_as;  adsP[0][t] = v * K_ad;
                    assP[1][t] = 0.f;       adsP[1][t] = 0.f;
                }
            } else {
                // proj-MFMA: h16 = W^T · hrow^T  (M=32 c, N=112 s, K=32)
                int ct = wave & 1, st = wave >> 1;       // ct 0..1, st 0..6
                int cb = ct * 16 + m;
                half8 A, B;
                #pragma unroll
                for (int j = 0; j < 8; j++) A[j] = (_Float16)W[(quad * 8 + j) * 32 + cb];
                B = *(const half8*)&hrow[(st * 16 + m) * HRS + quad * 8];
                if (l == 2) {                            // relu on layer-2 input
                    #pragma unroll
                    for (int j = 0; j < 8; j++)
                        B[j] = (B[j] > (_Float16)0.f) ? B[j] : (_Float16)0.f;
                }
                f32x4 D = {0.f, 0.f, 0.f, 0.f};
                D = __builtin_amdgcn_mfma_f32_16x16x32_f16(A, B, D, 0, 0, 0);
                float pa = 0.f, pd = 0.f;
                #pragma unroll
                for (int r = 0; r < 4; r++) {
                    int cc = ct * 16 + quad * 4 + r;
                    h16[cc * H16S + st * 16 + m] = (_Float16)D[r];
                    pa += D[r] * aS[cc];                 // L2-hot broadcast reads
                    pd += D[r] * aD[cc];
                }
                pa += __shfl_xor(pa, 16); pa += __shfl_xor(pa, 32);
                pd += __shfl_xor(pd, 16); pd += __shfl_xor(pd, 32);
                if (lane < 16) { assP[ct][st * 16 + m] = pa; adsP[ct][st * 16 + m] = pd; }
            }
        } else {
            // diag[d] = mean of incoming eatt (self-loop fill='mean'),
            // straight from global (coalesced across lanes per s-iteration)
            int dd = (wave - 14) * 64 + lane;            // 0..127
            if (dd < NPG) {
                float sum = 0.f;
                #pragma unroll 8
                for (int s = 0; s < NPG; s++) {
                    if (s != dd) {
                        float2 e = eg2[s * 110 + dd - (dd > s ? 1 : 0)];
                        sum += c0 * e.x + c1 * e.y;
                    }
                }
                diag[dd] = sum * (1.f / 110.f);
            }
        }
        __syncthreads();

        // ===== phase C: attention + aggregation MFMA (waves 0-6) =============
        if (wave < 7) {
            int d = wave * 16 + m;
            bool dok = (d < NPG);
            float adsv = dok ? (adsP[0][d] + adsP[1][d]) : 0.f;
            float dval = dok ? diag[d] : 0.f;
            f32x4 acc0 = {0.f, 0.f, 0.f, 0.f};
            f32x4 acc1 = {0.f, 0.f, 0.f, 0.f};
            float den = 0.f;
            #pragma unroll
            for (int kc = 0; kc < 4; kc++) {
                int s0 = kc * 32 + quad * 8;
                float4 p0 = *(const float4*)&assP[0][s0];
                float4 p1 = *(const float4*)&assP[1][s0];
                float4 q0 = *(const float4*)&assP[0][s0 + 4];
                float4 q1 = *(const float4*)&assP[1][s0 + 4];
                float asv[8] = {p0.x + p1.x, p0.y + p1.y, p0.z + p1.z, p0.w + p1.w,
                                q0.x + q1.x, q0.y + q1.y, q0.z + q1.z, q0.w + q1.w};
                half8 A;
                #pragma unroll
                for (int j = 0; j < 8; j++) {
                    int s = s0 + j;
                    float p = 0.f;
                    if (dok && s < NPG) {
                        float ev;
                        if (s == d) {
                            ev = dval;
                        } else {
                            float2 e = eg2[s * 110 + d - (d > s ? 1 : 0)];
                            ev = c0 * e.x + c1 * e.y;   // coalesced L2 read
                        }
                        float a = asv[j] + adsv + ev;
                        a = (a > 0.f) ? a : 0.2f * a;
                        p = __expf(a);
                    }
                    _Float16 ph = (_Float16)p;
                    A[j] = ph;
                    den += (float)ph;                    // f16-consistent den
                }
                half8 B0 = *(const half8*)&h16[(size_t)m * H16S + s0];
                half8 B1 = *(const half8*)&h16[(size_t)(16 + m) * H16S + s0];
                acc0 = __builtin_amdgcn_mfma_f32_16x16x32_f16(A, B0, acc0, 0, 0, 0);
                acc1 = __builtin_amdgcn_mfma_f32_16x16x32_f16(A, B1, acc1, 0, 0, 0);
            }
            den += __shfl_xor(den, 16);
            den += __shfl_xor(den, 32);

            if (l < 2) {                 // epilogue: new h -> hrow (row-major)
                #pragma unroll
                for (int r = 0; r < 4; r++) {
                    int dr = wave * 16 + quad * 4 + r;
                    float dn = __shfl(den, quad * 4 + r);
                    if (dr < NPG) {
                        float inv = 1.f / dn;
                        hrow[dr * HRS + m]      = (_Float16)(acc0[r] * inv + bsh[m]);
                        hrow[dr * HRS + 16 + m] = (_Float16)(acc1[r] * inv + bsh[16 + m]);
                    }
                }
            } else {                     // fused global_add_pool + linear
                float lw0 = linW[m], lw1 = linW[16 + m];
                float p = 0.f;
                #pragma unroll
                for (int r = 0; r < 4; r++) {
                    int dr = wave * 16 + quad * 4 + r;
                    float dn = __shfl(den, quad * 4 + r);
                    if (dr < NPG) {
                        float inv = 1.f / dn;
                        p += (acc0[r] * inv + bsh[m]) * lw0
                           + (acc1[r] * inv + bsh[16 + m]) * lw1;
                    }
                }
                #pragma unroll
                for (int off = 1; off < 64; off <<= 1) p += __shfl_xor(p, off);
                if (lane == 0) pool7[wave] = p;
            }
        }
        __syncthreads();
    }

    if (t == 0) {
        float s = 0.f;
        #pragma unroll
        for (int w = 0; w < 7; w++) s += pool7[w];
        out[g] = fmaxf(s + linb[0], 0.f);
    }
}

// ---------------------------------------------------------------------------
extern "C" void kernel_launch(void* const* d_in, const int* in_sizes, int n_in,
                              void* d_out, int out_size, void* d_ws, size_t ws_size,
                              hipStream_t stream) {
    // input order: x, edge_index, edge_attr, {W,as,ad,We,ae,b} x3, lin_W, lin_b
    const float* x  = (const float*)d_in[0];
    const float* ea = (const float*)d_in[2];
    gnn_all<<<BGR, 1024, 0, stream>>>(
        x, ea,
        (const float*)d_in[3],  (const float*)d_in[4],  (const float*)d_in[5],
        (const float*)d_in[6],  (const float*)d_in[7],  (const float*)d_in[8],
        (const float*)d_in[9],  (const float*)d_in[10], (const float*)d_in[11],
        (const float*)d_in[12], (const float*)d_in[13], (const float*)d_in[14],
        (const float*)d_in[15], (const float*)d_in[16], (const float*)d_in[17],
        (const float*)d_in[18], (const float*)d_in[19], (const float*)d_in[20],
        (const float*)d_in[21], (const float*)d_in[22],
        (float*)d_out);
}

// Round 12
// 138.219 us; speedup vs baseline: 1.6257x; 1.6257x over previous
//
#include <hip/hip_runtime.h>
#include <hip/hip_bf16.h>

// Problem constants (fixed by the reference setup)
#define BGR  128           // graphs
#define NPG  111           // nodes per graph
#define EPG  (NPG*(NPG-1)) // 12210 directed edges per graph
#define H16S 136           // h16 (transposed h) row stride in halfs, 16B-aligned
#define HRS  40            // hrow (row-major h) stride in halfs, 16B-aligned

typedef _Float16 half8 __attribute__((ext_vector_type(8)));
typedef float    f32x4 __attribute__((ext_vector_type(4)));

// ---------------------------------------------------------------------------
// ONE kernel: whole 3-layer GAT + pool. One 1024-thread block per graph.
// edge_attr staged raw into LDS ONCE; per-layer scalars folded at read.
// 2 barriers/layer: [proj-MFMA + ass/ads] -> [attention MFMA w/ inline diag].
__global__ __launch_bounds__(1024, 1) void
gnn_all(const float* __restrict__ x, const float* __restrict__ ea,
        const float* __restrict__ W0, const float* __restrict__ as0, const float* __restrict__ ad0,
        const float* __restrict__ We0, const float* __restrict__ ae0, const float* __restrict__ b0,
        const float* __restrict__ W1, const float* __restrict__ as1, const float* __restrict__ ad1,
        const float* __restrict__ We1, const float* __restrict__ ae1, const float* __restrict__ b1,
        const float* __restrict__ W2, const float* __restrict__ as2, const float* __restrict__ ad2,
        const float* __restrict__ We2, const float* __restrict__ ae2, const float* __restrict__ b2,
        const float* __restrict__ linW, const float* __restrict__ linb,
        float* __restrict__ out)
{
    int g = blockIdx.x;
    int t = threadIdx.x;
    int wave = t >> 6, lane = t & 63;
    int m = lane & 15, quad = lane >> 4;

    __shared__ float    eaL[EPG * 2];      // 97680 B: raw edge_attr [e][2]
    __shared__ _Float16 h16[32 * H16S];    // 8704 B: h transposed [c][s]
    __shared__ _Float16 hrow[112 * HRS];   // 8960 B: h row-major [s][c]
    __shared__ float assP[2][112];         // ass partials (ct 0/1)
    __shared__ float adsP[2][112];
    __shared__ float xsh[112];
    __shared__ float bsh[32];
    __shared__ float pool7[8];

    // ---- init: stage raw ea (coalesced float4), x; zero pads ----
    {
        const float4* eg4 = (const float4*)(ea + (size_t)g * EPG * 2);
        float4* dst = (float4*)eaL;
        for (int i = t; i < EPG / 2; i += 1024) dst[i] = eg4[i];
    }
    if (t < 112) xsh[t] = (t < NPG) ? x[g * NPG + t] : 0.f;
    for (int i = t; i < 32 * H16S; i += 1024) h16[i] = (_Float16)0.f;
    if (t < HRS) hrow[111 * HRS + t] = (_Float16)0.f;

    // layer-0 scalars (din=1): K_as = sum_c W0[c]*as0[c]; K_ad likewise
    float kr = (lane < 32) ? W0[lane] * as0[lane] : W0[lane & 31] * ad0[lane & 31];
    #pragma unroll
    for (int off = 1; off < 32; off <<= 1) kr += __shfl_xor(kr, off);
    float K_as = __shfl(kr, 0), K_ad = __shfl(kr, 32);
    __syncthreads();

    for (int l = 0; l < 3; l++) {
        const float* W  = (l == 0) ? W0  : ((l == 1) ? W1  : W2);
        const float* aS = (l == 0) ? as0 : ((l == 1) ? as1 : as2);
        const float* aD = (l == 0) ? ad0 : ((l == 1) ? ad1 : ad2);
        const float* Ne = (l == 0) ? We0 : ((l == 1) ? We1 : We2);
        const float* av = (l == 0) ? ae0 : ((l == 1) ? ae1 : ae2);
        const float* bb = (l == 0) ? b0  : ((l == 1) ? b1  : b2);

        // per-wave c0,c1 = We @ ae (redundant per wave; no LDS, no barrier)
        float red = Ne[(lane >> 5) * 32 + (lane & 31)] * av[lane & 31];
        #pragma unroll
        for (int off = 1; off < 32; off <<= 1) red += __shfl_xor(red, off);
        float c0 = __shfl(red, 0), c1 = __shfl(red, 32);

        if (t < 32) bsh[t] = bb[t];

        // ===== phase 1: projection (+ ass/ads partials) ======================
        if (wave < 14) {
            if (l == 0) {
                // outer product h^T[c][s] = x[s]*W[c]; 896 threads, sbase 0..27
                int c = t & 31, sbase = t >> 5;
                float wc = W[c];
                #pragma unroll
                for (int it = 0; it < 4; it++) {
                    int s = sbase + it * 28;             // 0..111
                    float hv = (s < NPG) ? xsh[s] * wc : 0.f;
                    h16[c * H16S + s] = (_Float16)hv;
                }
                if (t < 112) {                           // ass/ads via scalars
                    assP[0][t] = xsh[t] * K_as;  adsP[0][t] = xsh[t] * K_ad;
                    assP[1][t] = 0.f;            adsP[1][t] = 0.f;
                }
            } else {
                // proj-MFMA: h16 = W^T · hrow^T  (M=32 c, N=112 s, K=32)
                int ct = wave & 1, st = wave >> 1;       // ct 0..1, st 0..6
                int cb = ct * 16 + m;
                half8 A, B;
                #pragma unroll
                for (int j = 0; j < 8; j++) A[j] = (_Float16)W[(quad * 8 + j) * 32 + cb];
                B = *(const half8*)&hrow[(st * 16 + m) * HRS + quad * 8];
                if (l == 2) {                            // relu on layer-2 input
                    #pragma unroll
                    for (int j = 0; j < 8; j++)
                        B[j] = (B[j] > (_Float16)0.f) ? B[j] : (_Float16)0.f;
                }
                f32x4 D = {0.f, 0.f, 0.f, 0.f};
                D = __builtin_amdgcn_mfma_f32_16x16x32_f16(A, B, D, 0, 0, 0);
                float pa = 0.f, pd = 0.f;
                #pragma unroll
                for (int r = 0; r < 4; r++) {
                    int cc = ct * 16 + quad * 4 + r;
                    h16[cc * H16S + st * 16 + m] = (_Float16)D[r];
                    pa += D[r] * aS[cc];                 // L1-hot broadcast
                    pd += D[r] * aD[cc];
                }
                pa += __shfl_xor(pa, 16); pa += __shfl_xor(pa, 32);
                pd += __shfl_xor(pd, 16); pd += __shfl_xor(pd, 32);
                if (lane < 16) { assP[ct][st * 16 + m] = pa; adsP[ct][st * 16 + m] = pd; }
            }
        }
        __syncthreads();

        // ===== phase 2: attention MFMA (waves 0-6), diag inline ==============
        if (wave < 7) {
            int d = wave * 16 + m;
            bool dok = (d < NPG);
            float adsv = dok ? (adsP[0][d] + adsP[1][d]) : 0.f;

            // diag[d] = mean of incoming eatt (quad-split col sum from LDS)
            float dsum = 0.f;
            if (dok) {
                #pragma unroll 4
                for (int k = 0; k < 28; k++) {
                    int s = quad * 28 + k;
                    if (s < NPG && s != d) {
                        float2 e = *(const float2*)&eaL[2 * (s * 110 + d - (d > s ? 1 : 0))];
                        dsum += c0 * e.x + c1 * e.y;
                    }
                }
            }
            dsum += __shfl_xor(dsum, 16);
            dsum += __shfl_xor(dsum, 32);
            float dval = dsum * (1.f / 110.f);

            f32x4 acc0 = {0.f, 0.f, 0.f, 0.f};
            f32x4 acc1 = {0.f, 0.f, 0.f, 0.f};
            float den = 0.f;
            #pragma unroll
            for (int kc = 0; kc < 4; kc++) {
                int s0 = kc * 32 + quad * 8;
                float4 p0 = *(const float4*)&assP[0][s0];
                float4 p1 = *(const float4*)&assP[1][s0];
                float4 q0 = *(const float4*)&assP[0][s0 + 4];
                float4 q1 = *(const float4*)&assP[1][s0 + 4];
                float asv[8] = {p0.x + p1.x, p0.y + p1.y, p0.z + p1.z, p0.w + p1.w,
                                q0.x + q1.x, q0.y + q1.y, q0.z + q1.z, q0.w + q1.w};
                half8 A;
                #pragma unroll
                for (int j = 0; j < 8; j++) {
                    int s = s0 + j;
                    float p = 0.f;
                    if (dok && s < NPG) {
                        float ev;
                        if (s == d) {
                            ev = dval;
                        } else {
                            float2 e = *(const float2*)&eaL[2 * (s * 110 + d - (d > s ? 1 : 0))];
                            ev = c0 * e.x + c1 * e.y;
                        }
                        float a = asv[j] + adsv + ev;
                        a = (a > 0.f) ? a : 0.2f * a;
                        p = __expf(a);
                    }
                    _Float16 ph = (_Float16)p;
                    A[j] = ph;
                    den += (float)ph;                    // f16-consistent den
                }
                half8 B0 = *(const half8*)&h16[(size_t)m * H16S + s0];
                half8 B1 = *(const half8*)&h16[(size_t)(16 + m) * H16S + s0];
                acc0 = __builtin_amdgcn_mfma_f32_16x16x32_f16(A, B0, acc0, 0, 0, 0);
                acc1 = __builtin_amdgcn_mfma_f32_16x16x32_f16(A, B1, acc1, 0, 0, 0);
            }
            den += __shfl_xor(den, 16);
            den += __shfl_xor(den, 32);

            if (l < 2) {                 // epilogue: new h -> hrow (row-major)
                #pragma unroll
                for (int r = 0; r < 4; r++) {
                    int dr = wave * 16 + quad * 4 + r;
                    float dn = __shfl(den, quad * 4 + r);
                    if (dr < NPG) {
                        float inv = 1.f / dn;
                        hrow[dr * HRS + m]      = (_Float16)(acc0[r] * inv + bsh[m]);
                        hrow[dr * HRS + 16 + m] = (_Float16)(acc1[r] * inv + bsh[16 + m]);
                    }
                }
            } else {                     // fused global_add_pool + linear
                float lw0 = linW[m], lw1 = linW[16 + m];
                float p = 0.f;
                #pragma unroll
                for (int r = 0; r < 4; r++) {
                    int dr = wave * 16 + quad * 4 + r;
                    float dn = __shfl(den, quad * 4 + r);
                    if (dr < NPG) {
                        float inv = 1.f / dn;
                        p += (acc0[r] * inv + bsh[m]) * lw0
                           + (acc1[r] * inv + bsh[16 + m]) * lw1;
                    }
                }
                #pragma unroll
                for (int off = 1; off < 64; off <<= 1) p += __shfl_xor(p, off);
                if (lane == 0) pool7[wave] = p;
            }
        }
        __syncthreads();
    }

    if (t == 0) {
        float s = 0.f;
        #pragma unroll
        for (int w = 0; w < 7; w++) s += pool7[w];
        out[g] = fmaxf(s + linb[0], 0.f);
    }
}

// ---------------------------------------------------------------------------
extern "C" void kernel_launch(void* const* d_in, const int* in_sizes, int n_in,
                              void* d_out, int out_size, void* d_ws, size_t ws_size,
                              hipStream_t stream) {
    // input order: x, edge_index, edge_attr, {W,as,ad,We,ae,b} x3, lin_W, lin_b
    const float* x  = (const float*)d_in[0];
    const float* ea = (const float*)d_in[2];
    gnn_all<<<BGR, 1024, 0, stream>>>(
        x, ea,
        (const float*)d_in[3],  (const float*)d_in[4],  (const float*)d_in[5],
        (const float*)d_in[6],  (const float*)d_in[7],  (const float*)d_in[8],
        (const float*)d_in[9],  (const float*)d_in[10], (const float*)d_in[11],
        (const float*)d_in[12], (const float*)d_in[13], (const float*)d_in[14],
        (const float*)d_in[15], (const float*)d_in[16], (const float*)d_in[17],
        (const float*)d_in[18], (const float*)d_in[19], (const float*)d_in[20],
        (const float*)d_in[21], (const float*)d_in[22],
        (float*)d_out);
}

// Round 13
// 130.538 us; speedup vs baseline: 1.7213x; 1.0588x over previous
//
#include <hip/hip_runtime.h>
#include <hip/hip_bf16.h>

// Problem constants (fixed by the reference setup)
#define BGR  128           // graphs
#define NPG  111           // nodes per graph
#define EPG  (NPG*(NPG-1)) // 12210 directed edges per graph
#define H16S 136           // h16 (transposed h) row stride in halfs, 16B-aligned
#define HRS  40            // hrow (row-major h) stride in halfs, 16B-aligned

typedef _Float16 half8 __attribute__((ext_vector_type(8)));
typedef float    f32x4 __attribute__((ext_vector_type(4)));

// ---------------------------------------------------------------------------
// ONE kernel: whole 3-layer GAT + pool. One 512-thread block (8 waves) per
// graph. All layer-invariant quantities hoisted to init:
//   - raw edge_attr in LDS (eatt_l = c0_l*ea.x + c1_l*ea.y folded at read)
//   - colsum2 (for self-loop 'mean' diag; eatt is linear in ea)
//   - (c0,c1) per layer, as/ad/bias vectors, W1/W2 as f16
// 2 barriers per layer.
__global__ __launch_bounds__(512, 1) void
gnn_all(const float* __restrict__ x, const float* __restrict__ ea,
        const float* __restrict__ W0, const float* __restrict__ as0, const float* __restrict__ ad0,
        const float* __restrict__ We0, const float* __restrict__ ae0, const float* __restrict__ b0,
        const float* __restrict__ W1, const float* __restrict__ as1, const float* __restrict__ ad1,
        const float* __restrict__ We1, const float* __restrict__ ae1, const float* __restrict__ b1,
        const float* __restrict__ W2, const float* __restrict__ as2, const float* __restrict__ ad2,
        const float* __restrict__ We2, const float* __restrict__ ae2, const float* __restrict__ b2,
        const float* __restrict__ linW, const float* __restrict__ linb,
        float* __restrict__ out)
{
    int g = blockIdx.x;
    int t = threadIdx.x;
    int wave = t >> 6, lane = t & 63;
    int m = lane & 15, quad = lane >> 4;

    __shared__ float    eaL[EPG * 2];       // 97680 B: raw edge_attr [e][2]
    __shared__ _Float16 h16[32 * H16S];     // 8704 B: h transposed [c][s]
    __shared__ _Float16 hrow[112 * HRS];    // 8960 B: h row-major [s][c]
    __shared__ _Float16 WL[2][1024];        // 4096 B: W1,W2 as f16
    __shared__ float    assP[2][128];       // ass partials (ct 0/1)
    __shared__ float    adsP[2][128];
    __shared__ float    colsum2[112][2];    // layer-independent column sums
    __shared__ float    cvL[3][2];          // (c0,c1) per layer
    __shared__ float    aswL[3][32], adwL[3][32], bshL[3][32];
    __shared__ float    xsh[112];
    __shared__ float    pool7[8];

    // ================= init (everything layer-invariant) =================
    {
        const float4* eg4 = (const float4*)(ea + (size_t)g * EPG * 2);
        float4* dst = (float4*)eaL;
        for (int i = t; i < EPG / 2; i += 512) dst[i] = eg4[i];
    }
    if (t < 112) xsh[t] = (t < NPG) ? x[g * NPG + t] : 0.f;
    // zero h16 pad cols 111..135 (col 111 rewritten by proj each layer)
    for (int i = t; i < 32 * 25; i += 512) {
        int c = i / 25, s = 111 + (i - c * 25);
        h16[c * H16S + s] = (_Float16)0.f;
    }
    if (t < HRS) hrow[111 * HRS + t] = (_Float16)0.f;
    for (int i = t; i < 1024; i += 512) {
        WL[0][i] = (_Float16)W1[i];
        WL[1][i] = (_Float16)W2[i];
    }
    if (t < 96) {
        int l = t >> 5, c = t & 31;
        const float* aSp = (l == 0) ? as0 : ((l == 1) ? as1 : as2);
        const float* aDp = (l == 0) ? ad0 : ((l == 1) ? ad1 : ad2);
        const float* bbp = (l == 0) ? b0  : ((l == 1) ? b1  : b2);
        aswL[l][c] = aSp[c]; adwL[l][c] = aDp[c]; bshL[l][c] = bbp[c];
    }
    if (t < 192) {               // (c0,c1) = We_l @ ae_l, waves 0-2 (uniform)
        int l = t >> 6;
        const float* Ne = (l == 0) ? We0 : ((l == 1) ? We1 : We2);
        const float* av = (l == 0) ? ae0 : ((l == 1) ? ae1 : ae2);
        float red = Ne[(lane >> 5) * 32 + (lane & 31)] * av[lane & 31];
        #pragma unroll
        for (int off = 1; off < 32; off <<= 1) red += __shfl_xor(red, off);
        if (lane == 0)  cvL[l][0] = red;
        if (lane == 32) cvL[l][1] = red;
    }
    // layer-0 din=1 scalars: K_as = sum_c W0[c]*as0[c]; K_ad likewise
    float K_as = 0.f, K_ad = 0.f;
    if (wave < 2) {
        float kr = (lane < 32) ? W0[lane] * as0[lane]
                               : W0[lane & 31] * ad0[lane & 31];
        #pragma unroll
        for (int off = 1; off < 32; off <<= 1) kr += __shfl_xor(kr, off);
        K_as = __shfl(kr, 0); K_ad = __shfl(kr, 32);
    }
    __syncthreads();   // eaL / xsh / params ready

    // ========================= layer loop ================================
    for (int l = 0; l < 3; l++) {
        float2 cv = *(const float2*)&cvL[l][0];
        float c0 = cv.x, c1 = cv.y;

        // ----- phase 1: projection (+ ass/ads partials); l==0 also colsum2 --
        if (l == 0) {
            int c = t & 31, sb = t >> 5;           // sb 0..15
            float wc = W0[c];
            #pragma unroll
            for (int it = 0; it < 7; it++) {
                int s = sb + it * 16;              // 0..111
                float hv = (s < NPG) ? xsh[s] * wc : 0.f;
                h16[c * H16S + s] = (_Float16)hv;
            }
            if (t < 112) {
                assP[0][t] = xsh[t] * K_as;  adsP[0][t] = xsh[t] * K_ad;
                assP[1][t] = 0.f;            adsP[1][t] = 0.f;
            }
            // colsum2 (once): quad-split column sums of raw ea, excl. diagonal
            if (wave < 7) {
                int d = wave * 16 + m;
                bool dok = (d < NPG);
                float sx = 0.f, sy = 0.f;
                if (dok) {
                    #pragma unroll 4
                    for (int k = 0; k < 28; k++) {
                        int s = quad * 28 + k;
                        if (s < NPG && s != d) {
                            float2 e = *(const float2*)&eaL[2 * (s * 110 + d - (d > s ? 1 : 0))];
                            sx += e.x; sy += e.y;
                        }
                    }
                }
                sx += __shfl_xor(sx, 16); sx += __shfl_xor(sx, 32);
                sy += __shfl_xor(sy, 16); sy += __shfl_xor(sy, 32);
                if (lane < 16 && dok) { colsum2[d][0] = sx; colsum2[d][1] = sy; }
            }
        } else {
            // proj-MFMA: h16 = W^T · hrow^T (M=32 c, N=112 s, K=32); 14 tiles
            for (int tile = wave; tile < 14; tile += 8) {
                int ct = tile & 1, st = tile >> 1;
                int cb = ct * 16 + m;
                half8 A, B;
                #pragma unroll
                for (int j = 0; j < 8; j++) A[j] = WL[l - 1][(quad * 8 + j) * 32 + cb];
                B = *(const half8*)&hrow[(st * 16 + m) * HRS + quad * 8];
                if (l == 2) {                      // relu on layer-2 input
                    #pragma unroll
                    for (int j = 0; j < 8; j++)
                        B[j] = (B[j] > (_Float16)0.f) ? B[j] : (_Float16)0.f;
                }
                f32x4 D = {0.f, 0.f, 0.f, 0.f};
                D = __builtin_amdgcn_mfma_f32_16x16x32_f16(A, B, D, 0, 0, 0);
                float pa = 0.f, pd = 0.f;
                #pragma unroll
                for (int r = 0; r < 4; r++) {
                    int cc = ct * 16 + quad * 4 + r;
                    h16[cc * H16S + st * 16 + m] = (_Float16)D[r];
                    pa += D[r] * aswL[l][cc];
                    pd += D[r] * adwL[l][cc];
                }
                pa += __shfl_xor(pa, 16); pa += __shfl_xor(pa, 32);
                pd += __shfl_xor(pd, 16); pd += __shfl_xor(pd, 32);
                if (lane < 16) { assP[ct][st * 16 + m] = pa; adsP[ct][st * 16 + m] = pd; }
            }
        }
        __syncthreads();

        // ----- phase 2: attention MFMA (waves 0-6), diag from colsum2 -------
        if (wave < 7) {
            int d = wave * 16 + m;
            bool dok = (d < NPG);
            float adsv = dok ? (adsP[0][d] + adsP[1][d]) : 0.f;
            float dval = 0.f;
            if (dok) {
                float2 cs = *(const float2*)&colsum2[d][0];
                dval = (c0 * cs.x + c1 * cs.y) * (1.f / 110.f);
            }

            f32x4 acc0 = {0.f, 0.f, 0.f, 0.f};
            f32x4 acc1 = {0.f, 0.f, 0.f, 0.f};
            float den = 0.f;
            #pragma unroll
            for (int kc = 0; kc < 4; kc++) {
                int s0 = kc * 32 + quad * 8;
                float4 p0 = *(const float4*)&assP[0][s0];
                float4 p1 = *(const float4*)&assP[1][s0];
                float4 q0 = *(const float4*)&assP[0][s0 + 4];
                float4 q1 = *(const float4*)&assP[1][s0 + 4];
                float asv[8] = {p0.x + p1.x, p0.y + p1.y, p0.z + p1.z, p0.w + p1.w,
                                q0.x + q1.x, q0.y + q1.y, q0.z + q1.z, q0.w + q1.w};
                half8 A;
                #pragma unroll
                for (int j = 0; j < 8; j++) {
                    int s = s0 + j;
                    float p = 0.f;
                    if (dok && s < NPG) {
                        float ev;
                        if (s == d) {
                            ev = dval;
                        } else {
                            float2 e = *(const float2*)&eaL[2 * (s * 110 + d - (d > s ? 1 : 0))];
                            ev = c0 * e.x + c1 * e.y;
                        }
                        float a = asv[j] + adsv + ev;
                        a = (a > 0.f) ? a : 0.2f * a;
                        p = __expf(a);
                    }
                    _Float16 ph = (_Float16)p;
                    A[j] = ph;
                    den += (float)ph;              // f16-consistent denominator
                }
                half8 B0 = *(const half8*)&h16[(size_t)m * H16S + s0];
                half8 B1 = *(const half8*)&h16[(size_t)(16 + m) * H16S + s0];
                acc0 = __builtin_amdgcn_mfma_f32_16x16x32_f16(A, B0, acc0, 0, 0, 0);
                acc1 = __builtin_amdgcn_mfma_f32_16x16x32_f16(A, B1, acc1, 0, 0, 0);
            }
            den += __shfl_xor(den, 16);
            den += __shfl_xor(den, 32);

            if (l < 2) {                 // epilogue: new h -> hrow (row-major)
                #pragma unroll
                for (int r = 0; r < 4; r++) {
                    int dr = wave * 16 + quad * 4 + r;
                    float dn = __shfl(den, quad * 4 + r);
                    if (dr < NPG) {
                        float inv = 1.f / dn;
                        hrow[dr * HRS + m]      = (_Float16)(acc0[r] * inv + bshL[l][m]);
                        hrow[dr * HRS + 16 + m] = (_Float16)(acc1[r] * inv + bshL[l][16 + m]);
                    }
                }
            } else {                     // fused global_add_pool + linear
                float lw0 = linW[m], lw1 = linW[16 + m];
                float p = 0.f;
                #pragma unroll
                for (int r = 0; r < 4; r++) {
                    int dr = wave * 16 + quad * 4 + r;
                    float dn = __shfl(den, quad * 4 + r);
                    if (dr < NPG) {
                        float inv = 1.f / dn;
                        p += (acc0[r] * inv + bshL[2][m]) * lw0
                           + (acc1[r] * inv + bshL[2][16 + m]) * lw1;
                    }
                }
                #pragma unroll
                for (int off = 1; off < 64; off <<= 1) p += __shfl_xor(p, off);
                if (lane == 0) pool7[wave] = p;
            }
        }
        __syncthreads();
    }

    if (t == 0) {
        float s = 0.f;
        #pragma unroll
        for (int w = 0; w < 7; w++) s += pool7[w];
        out[g] = fmaxf(s + linb[0], 0.f);
    }
}

// ---------------------------------------------------------------------------
extern "C" void kernel_launch(void* const* d_in, const int* in_sizes, int n_in,
                              void* d_out, int out_size, void* d_ws, size_t ws_size,
                              hipStream_t stream) {
    // input order: x, edge_index, edge_attr, {W,as,ad,We,ae,b} x3, lin_W, lin_b
    const float* x  = (const float*)d_in[0];
    const float* ea = (const float*)d_in[2];
    gnn_all<<<BGR, 512, 0, stream>>>(
        x, ea,
        (const float*)d_in[3],  (const float*)d_in[4],  (const float*)d_in[5],
        (const float*)d_in[6],  (const float*)d_in[7],  (const float*)d_in[8],
        (const float*)d_in[9],  (const float*)d_in[10], (const float*)d_in[11],
        (const float*)d_in[12], (const float*)d_in[13], (const float*)d_in[14],
        (const float*)d_in[15], (const float*)d_in[16], (const float*)d_in[17],
        (const float*)d_in[18], (const float*)d_in[19], (const float*)d_in[20],
        (const float*)d_in[21], (const float*)d_in[22],
        (float*)d_out);
}

// Round 14
// 129.574 us; speedup vs baseline: 1.7341x; 1.0074x over previous
//
#include <hip/hip_runtime.h>
#include <hip/hip_bf16.h>

// Problem constants (fixed by the reference setup)
#define BGR  128           // graphs
#define NPG  111           // nodes per graph
#define EPG  (NPG*(NPG-1)) // 12210 directed edges per graph
#define H16S 136           // h16 (transposed h) row stride in halfs, 16B-aligned
#define HRS  40            // hrow (row-major h) stride in halfs, 16B-aligned

typedef _Float16 half8  __attribute__((ext_vector_type(8)));
typedef _Float16 half4v __attribute__((ext_vector_type(4)));
typedef _Float16 half2v __attribute__((ext_vector_type(2)));
typedef float    f32x4  __attribute__((ext_vector_type(4)));

// ---------------------------------------------------------------------------
// ONE kernel: whole 3-layer GAT + pool. One 512-thread block (8 waves) per
// graph. Structure identical to round 13 (best-known); change: edge_attr held
// in LDS as f16 pairs (halves staging LDS writes + phase-2 read bytes).
__global__ __launch_bounds__(512, 1) void
gnn_all(const float* __restrict__ x, const float* __restrict__ ea,
        const float* __restrict__ W0, const float* __restrict__ as0, const float* __restrict__ ad0,
        const float* __restrict__ We0, const float* __restrict__ ae0, const float* __restrict__ b0,
        const float* __restrict__ W1, const float* __restrict__ as1, const float* __restrict__ ad1,
        const float* __restrict__ We1, const float* __restrict__ ae1, const float* __restrict__ b1,
        const float* __restrict__ W2, const float* __restrict__ as2, const float* __restrict__ ad2,
        const float* __restrict__ We2, const float* __restrict__ ae2, const float* __restrict__ b2,
        const float* __restrict__ linW, const float* __restrict__ linb,
        float* __restrict__ out)
{
    int g = blockIdx.x;
    int t = threadIdx.x;
    int wave = t >> 6, lane = t & 63;
    int m = lane & 15, quad = lane >> 4;

    __shared__ _Float16 eaL[EPG * 2];       // 48840 B: edge_attr as f16 [e][2]
    __shared__ _Float16 h16[32 * H16S];     // 8704 B: h transposed [c][s]
    __shared__ _Float16 hrow[112 * HRS];    // 8960 B: h row-major [s][c]
    __shared__ _Float16 WL[2][1024];        // 4096 B: W1,W2 as f16
    __shared__ float    assP[2][128];       // ass partials (ct 0/1)
    __shared__ float    adsP[2][128];
    __shared__ float    colsum2[112][2];    // layer-independent column sums
    __shared__ float    cvL[3][2];          // (c0,c1) per layer
    __shared__ float    aswL[3][32], adwL[3][32], bshL[3][32];
    __shared__ float    xsh[112];
    __shared__ float    pool7[8];

    // ================= init (everything layer-invariant) =================
    {
        const float4* eg4 = (const float4*)(ea + (size_t)g * EPG * 2);
        for (int i = t; i < EPG / 2; i += 512) {     // 2 edges per iter
            float4 v = eg4[i];
            half4v h4 = {(_Float16)v.x, (_Float16)v.y, (_Float16)v.z, (_Float16)v.w};
            *(half4v*)&eaL[4 * i] = h4;
        }
    }
    if (t < 112) xsh[t] = (t < NPG) ? x[g * NPG + t] : 0.f;
    // zero h16 pad cols 111..135 (col 111 rewritten by proj each layer)
    for (int i = t; i < 32 * 25; i += 512) {
        int c = i / 25, s = 111 + (i - c * 25);
        h16[c * H16S + s] = (_Float16)0.f;
    }
    if (t < HRS) hrow[111 * HRS + t] = (_Float16)0.f;
    for (int i = t; i < 1024; i += 512) {
        WL[0][i] = (_Float16)W1[i];
        WL[1][i] = (_Float16)W2[i];
    }
    if (t < 96) {
        int l = t >> 5, c = t & 31;
        const float* aSp = (l == 0) ? as0 : ((l == 1) ? as1 : as2);
        const float* aDp = (l == 0) ? ad0 : ((l == 1) ? ad1 : ad2);
        const float* bbp = (l == 0) ? b0  : ((l == 1) ? b1  : b2);
        aswL[l][c] = aSp[c]; adwL[l][c] = aDp[c]; bshL[l][c] = bbp[c];
    }
    if (t < 192) {               // (c0,c1) = We_l @ ae_l, waves 0-2 (uniform)
        int l = t >> 6;
        const float* Ne = (l == 0) ? We0 : ((l == 1) ? We1 : We2);
        const float* av = (l == 0) ? ae0 : ((l == 1) ? ae1 : ae2);
        float red = Ne[(lane >> 5) * 32 + (lane & 31)] * av[lane & 31];
        #pragma unroll
        for (int off = 1; off < 32; off <<= 1) red += __shfl_xor(red, off);
        if (lane == 0)  cvL[l][0] = red;
        if (lane == 32) cvL[l][1] = red;
    }
    // layer-0 din=1 scalars: K_as = sum_c W0[c]*as0[c]; K_ad likewise
    float K_as = 0.f, K_ad = 0.f;
    if (wave < 2) {
        float kr = (lane < 32) ? W0[lane] * as0[lane]
                               : W0[lane & 31] * ad0[lane & 31];
        #pragma unroll
        for (int off = 1; off < 32; off <<= 1) kr += __shfl_xor(kr, off);
        K_as = __shfl(kr, 0); K_ad = __shfl(kr, 32);
    }
    __syncthreads();   // eaL / xsh / params ready

    // ========================= layer loop ================================
    for (int l = 0; l < 3; l++) {
        float2 cv = *(const float2*)&cvL[l][0];
        float c0 = cv.x, c1 = cv.y;

        // ----- phase 1: projection (+ ass/ads partials); l==0 also colsum2 --
        if (l == 0) {
            int c = t & 31, sb = t >> 5;           // sb 0..15
            float wc = W0[c];
            #pragma unroll
            for (int it = 0; it < 7; it++) {
                int s = sb + it * 16;              // 0..111
                float hv = (s < NPG) ? xsh[s] * wc : 0.f;
                h16[c * H16S + s] = (_Float16)hv;
            }
            if (t < 112) {
                assP[0][t] = xsh[t] * K_as;  adsP[0][t] = xsh[t] * K_ad;
                assP[1][t] = 0.f;            adsP[1][t] = 0.f;
            }
            // colsum2 (once): quad-split column sums of f16 ea, excl. diagonal
            if (wave < 7) {
                int d = wave * 16 + m;
                bool dok = (d < NPG);
                float sx = 0.f, sy = 0.f;
                if (dok) {
                    #pragma unroll 4
                    for (int k = 0; k < 28; k++) {
                        int s = quad * 28 + k;
                        if (s < NPG && s != d) {
                            half2v e = *(const half2v*)&eaL[2 * (s * 110 + d - (d > s ? 1 : 0))];
                            sx += (float)e[0]; sy += (float)e[1];
                        }
                    }
                }
                sx += __shfl_xor(sx, 16); sx += __shfl_xor(sx, 32);
                sy += __shfl_xor(sy, 16); sy += __shfl_xor(sy, 32);
                if (lane < 16 && dok) { colsum2[d][0] = sx; colsum2[d][1] = sy; }
            }
        } else {
            // proj-MFMA: h16 = W^T · hrow^T (M=32 c, N=112 s, K=32); 14 tiles
            for (int tile = wave; tile < 14; tile += 8) {
                int ct = tile & 1, st = tile >> 1;
                int cb = ct * 16 + m;
                half8 A, B;
                #pragma unroll
                for (int j = 0; j < 8; j++) A[j] = WL[l - 1][(quad * 8 + j) * 32 + cb];
                B = *(const half8*)&hrow[(st * 16 + m) * HRS + quad * 8];
                if (l == 2) {                      // relu on layer-2 input
                    #pragma unroll
                    for (int j = 0; j < 8; j++)
                        B[j] = (B[j] > (_Float16)0.f) ? B[j] : (_Float16)0.f;
                }
                f32x4 D = {0.f, 0.f, 0.f, 0.f};
                D = __builtin_amdgcn_mfma_f32_16x16x32_f16(A, B, D, 0, 0, 0);
                float pa = 0.f, pd = 0.f;
                #pragma unroll
                for (int r = 0; r < 4; r++) {
                    int cc = ct * 16 + quad * 4 + r;
                    h16[cc * H16S + st * 16 + m] = (_Float16)D[r];
                    pa += D[r] * aswL[l][cc];
                    pd += D[r] * adwL[l][cc];
                }
                pa += __shfl_xor(pa, 16); pa += __shfl_xor(pa, 32);
                pd += __shfl_xor(pd, 16); pd += __shfl_xor(pd, 32);
                if (lane < 16) { assP[ct][st * 16 + m] = pa; adsP[ct][st * 16 + m] = pd; }
            }
        }
        __syncthreads();

        // ----- phase 2: attention MFMA (waves 0-6), diag from colsum2 -------
        if (wave < 7) {
            int d = wave * 16 + m;
            bool dok = (d < NPG);
            float adsv = dok ? (adsP[0][d] + adsP[1][d]) : 0.f;
            float dval = 0.f;
            if (dok) {
                float2 cs = *(const float2*)&colsum2[d][0];
                dval = (c0 * cs.x + c1 * cs.y) * (1.f / 110.f);
            }

            f32x4 acc0 = {0.f, 0.f, 0.f, 0.f};
            f32x4 acc1 = {0.f, 0.f, 0.f, 0.f};
            float den = 0.f;
            #pragma unroll
            for (int kc = 0; kc < 4; kc++) {
                int s0 = kc * 32 + quad * 8;
                float4 p0 = *(const float4*)&assP[0][s0];
                float4 p1 = *(const float4*)&assP[1][s0];
                float4 q0 = *(const float4*)&assP[0][s0 + 4];
                float4 q1 = *(const float4*)&assP[1][s0 + 4];
                float asv[8] = {p0.x + p1.x, p0.y + p1.y, p0.z + p1.z, p0.w + p1.w,
                                q0.x + q1.x, q0.y + q1.y, q0.z + q1.z, q0.w + q1.w};
                half8 A;
                #pragma unroll
                for (int j = 0; j < 8; j++) {
                    int s = s0 + j;
                    float p = 0.f;
                    if (dok && s < NPG) {
                        float ev;
                        if (s == d) {
                            ev = dval;
                        } else {
                            half2v e = *(const half2v*)&eaL[2 * (s * 110 + d - (d > s ? 1 : 0))];
                            ev = c0 * (float)e[0] + c1 * (float)e[1];
                        }
                        float a = asv[j] + adsv + ev;
                        a = (a > 0.f) ? a : 0.2f * a;
                        p = __expf(a);
                    }
                    _Float16 ph = (_Float16)p;
                    A[j] = ph;
                    den += (float)ph;              // f16-consistent denominator
                }
                half8 B0 = *(const half8*)&h16[(size_t)m * H16S + s0];
                half8 B1 = *(const half8*)&h16[(size_t)(16 + m) * H16S + s0];
                acc0 = __builtin_amdgcn_mfma_f32_16x16x32_f16(A, B0, acc0, 0, 0, 0);
                acc1 = __builtin_amdgcn_mfma_f32_16x16x32_f16(A, B1, acc1, 0, 0, 0);
            }
            den += __shfl_xor(den, 16);
            den += __shfl_xor(den, 32);

            if (l < 2) {                 // epilogue: new h -> hrow (row-major)
                #pragma unroll
                for (int r = 0; r < 4; r++) {
                    int dr = wave * 16 + quad * 4 + r;
                    float dn = __shfl(den, quad * 4 + r);
                    if (dr < NPG) {
                        float inv = 1.f / dn;
                        hrow[dr * HRS + m]      = (_Float16)(acc0[r] * inv + bshL[l][m]);
                        hrow[dr * HRS + 16 + m] = (_Float16)(acc1[r] * inv + bshL[l][16 + m]);
                    }
                }
            } else {                     // fused global_add_pool + linear
                float lw0 = linW[m], lw1 = linW[16 + m];
                float p = 0.f;
                #pragma unroll
                for (int r = 0; r < 4; r++) {
                    int dr = wave * 16 + quad * 4 + r;
                    float dn = __shfl(den, quad * 4 + r);
                    if (dr < NPG) {
                        float inv = 1.f / dn;
                        p += (acc0[r] * inv + bshL[2][m]) * lw0
                           + (acc1[r] * inv + bshL[2][16 + m]) * lw1;
                    }
                }
                #pragma unroll
                for (int off = 1; off < 64; off <<= 1) p += __shfl_xor(p, off);
                if (lane == 0) pool7[wave] = p;
            }
        }
        __syncthreads();
    }

    if (t == 0) {
        float s = 0.f;
        #pragma unroll
        for (int w = 0; w < 7; w++) s += pool7[w];
        out[g] = fmaxf(s + linb[0], 0.f);
    }
}

// ---------------------------------------------------------------------------
extern "C" void kernel_launch(void* const* d_in, const int* in_sizes, int n_in,
                              void* d_out, int out_size, void* d_ws, size_t ws_size,
                              hipStream_t stream) {
    // input order: x, edge_index, edge_attr, {W,as,ad,We,ae,b} x3, lin_W, lin_b
    const float* x  = (const float*)d_in[0];
    const float* ea = (const float*)d_in[2];
    gnn_all<<<BGR, 512, 0, stream>>>(
        x, ea,
        (const float*)d_in[3],  (const float*)d_in[4],  (const float*)d_in[5],
        (const float*)d_in[6],  (const float*)d_in[7],  (const float*)d_in[8],
        (const float*)d_in[9],  (const float*)d_in[10], (const float*)d_in[11],
        (const float*)d_in[12], (const float*)d_in[13], (const float*)d_in[14],
        (const float*)d_in[15], (const float*)d_in[16], (const float*)d_in[17],
        (const float*)d_in[18], (const float*)d_in[19], (const float*)d_in[20],
        (const float*)d_in[21], (const float*)d_in[22],
        (float*)d_out);
}